// Round 1
// baseline (31.516 us; speedup 1.0000x reference)
//
#include <hip/hip_runtime.h>

#define G 512
#define N 24
#define D (G*N)
#define DIM 64
#define HL 3
#define OL 2

__global__ __launch_bounds__(256)
void gnn_mol_kernel(const int* __restrict__ fp,
                    const float* __restrict__ A,
                    const float* __restrict__ emb,
                    const float* __restrict__ W_fp,
                    const float* __restrict__ b_fp,
                    const float* __restrict__ W_out,
                    const float* __restrict__ b_out,
                    const float* __restrict__ W_prop,
                    const float* __restrict__ b_prop,
                    float* __restrict__ out)
{
    const int g = blockIdx.x;
    const int t = threadIdx.x;
    const int j = t & 63;      // column
    const int w = t >> 6;      // wave id 0..3; wave owns atoms w, w+4, ..., w+20

    __shared__ float xs[N][DIM];   // current x
    __shared__ float hs[N][DIM];   // relu(linear(x))
    __shared__ float As[N * N];    // 24x24 adjacency block
    __shared__ float ps[4][DIM];   // per-wave partial column sums
    __shared__ float ms[DIM];      // mol vector
    __shared__ float ys[DIM];      // hidden of out-MLP
    __shared__ float zs[DIM];

    // ---- load the diagonal A block only (NEVER stream full 604MB A) ----
    const long srow = (long)g * N;
    for (int idx = t; idx < N * N; idx += 256) {
        int r = idx / N, c = idx - r * N;
        As[idx] = A[(srow + r) * (long)D + (srow + c)];
    }

    // ---- embedding gather: x[a][j] = emb[fp[a]][j] ----
    float xv[6];
    #pragma unroll
    for (int r = 0; r < 6; ++r) {
        int a = w + 4 * r;
        int f = fp[g * N + a];
        float v = emb[f * DIM + j];
        xv[r] = v;
        xs[a][j] = v;
    }
    __syncthreads();

    // ---- 3 message-passing rounds ----
    for (int layer = 0; layer < HL; ++layer) {
        // W row j -> registers (global, L1/L2 cached; same 16KB for every block)
        const float* Wl = W_fp + layer * DIM * DIM + j * DIM;
        float wreg[DIM];
        #pragma unroll
        for (int k4 = 0; k4 < 16; ++k4) {
            float4 wv = *(const float4*)(Wl + 4 * k4);
            wreg[4*k4+0] = wv.x; wreg[4*k4+1] = wv.y;
            wreg[4*k4+2] = wv.z; wreg[4*k4+3] = wv.w;
        }
        float bias = b_fp[layer * DIM + j];

        // h[a][j] = relu( sum_k x[a][k] * W[j][k] + b[j] )
        float h[6];
        #pragma unroll
        for (int r = 0; r < 6; ++r) h[r] = bias;
        #pragma unroll
        for (int k4 = 0; k4 < 16; ++k4) {
            #pragma unroll
            for (int r = 0; r < 6; ++r) {
                int a = w + 4 * r;
                float4 xa = *(const float4*)(&xs[a][4 * k4]);  // wave-uniform broadcast
                h[r] += xa.x * wreg[4*k4+0] + xa.y * wreg[4*k4+1]
                      + xa.z * wreg[4*k4+2] + xa.w * wreg[4*k4+3];
            }
        }
        #pragma unroll
        for (int r = 0; r < 6; ++r) {
            h[r] = fmaxf(h[r], 0.f);
            hs[w + 4 * r][j] = h[r];
        }
        __syncthreads();

        // x[a][j] += sum_b A[a][b] * h[b][j]
        float hb[N];
        #pragma unroll
        for (int b = 0; b < N; ++b) hb[b] = hs[b][j];   // lane-consecutive, conflict-free
        #pragma unroll
        for (int r = 0; r < 6; ++r) {
            int a = w + 4 * r;
            float acc = 0.f;
            #pragma unroll
            for (int b4 = 0; b4 < 6; ++b4) {
                float4 av = *(const float4*)(&As[a * N + 4 * b4]);  // broadcast
                acc += av.x * hb[4*b4+0] + av.y * hb[4*b4+1]
                     + av.z * hb[4*b4+2] + av.w * hb[4*b4+3];
            }
            xv[r] += acc;
            xs[a][j] = xv[r];
        }
        __syncthreads();
    }

    // ---- segment sum: mol[j] = sum_a x[a][j] ----
    float partial = 0.f;
    #pragma unroll
    for (int r = 0; r < 6; ++r) partial += xv[r];
    ps[w][j] = partial;
    __syncthreads();
    if (t < DIM) ms[t] = ps[0][t] + ps[1][t] + ps[2][t] + ps[3][t];
    __syncthreads();

    // ---- output MLP layer 0 ----
    if (t < DIM) {
        float acc = b_out[t];
        #pragma unroll
        for (int k4 = 0; k4 < 16; ++k4) {
            float4 mv = *(const float4*)(&ms[4 * k4]);
            const float* Wr = W_out + t * DIM + 4 * k4;
            acc += mv.x * Wr[0] + mv.y * Wr[1] + mv.z * Wr[2] + mv.w * Wr[3];
        }
        ys[t] = fmaxf(acc, 0.f);
    }
    __syncthreads();

    // ---- output MLP layer 1 ----
    if (t < DIM) {
        float acc = b_out[DIM + t];
        #pragma unroll
        for (int k4 = 0; k4 < 16; ++k4) {
            float4 yv = *(const float4*)(&ys[4 * k4]);
            const float* Wr = W_out + DIM * DIM + t * DIM + 4 * k4;
            acc += yv.x * Wr[0] + yv.y * Wr[1] + yv.z * Wr[2] + yv.w * Wr[3];
        }
        zs[t] = fmaxf(acc, 0.f);
    }
    __syncthreads();

    // ---- property head: out[g][p] = sum_k y[k] * W_prop[p][k] + b_prop[p] ----
    if (t < 2) {
        float acc = b_prop[t];
        #pragma unroll
        for (int k4 = 0; k4 < 16; ++k4) {
            float4 zv = *(const float4*)(&zs[4 * k4]);
            const float* Wr = W_prop + t * DIM + 4 * k4;
            acc += zv.x * Wr[0] + zv.y * Wr[1] + zv.z * Wr[2] + zv.w * Wr[3];
        }
        out[g * 2 + t] = acc;
    }
}

extern "C" void kernel_launch(void* const* d_in, const int* in_sizes, int n_in,
                              void* d_out, int out_size, void* d_ws, size_t ws_size,
                              hipStream_t stream) {
    const int*   fp     = (const int*)  d_in[0];
    // d_in[1] segment_ids: unused (implied by block index)
    const float* A      = (const float*)d_in[2];
    const float* emb    = (const float*)d_in[3];
    const float* W_fp   = (const float*)d_in[4];
    const float* b_fp   = (const float*)d_in[5];
    const float* W_out  = (const float*)d_in[6];
    const float* b_out  = (const float*)d_in[7];
    const float* W_prop = (const float*)d_in[8];
    const float* b_prop = (const float*)d_in[9];
    float* out = (float*)d_out;

    gnn_mol_kernel<<<G, 256, 0, stream>>>(fp, A, emb, W_fp, b_fp,
                                          W_out, b_out, W_prop, b_prop, out);
}